// Round 1
// baseline (512.056 us; speedup 1.0000x reference)
//
#include <hip/hip_runtime.h>
#include <hip/hip_bf16.h>

typedef __attribute__((ext_vector_type(8))) short bf16x8;
typedef __attribute__((ext_vector_type(4))) float f32x4;

#define NB 2
#define NS 4096
#define ND 512
#define NH 8

__device__ __forceinline__ unsigned short f2bf(float f) {
  unsigned int u = __float_as_uint(f);
  u += 0x7fffu + ((u >> 16) & 1u);
  return (unsigned short)(u >> 16);
}

// ---------------- pack: fp32 -> bf16, pre-transpose weights ----------------
__global__ void pack_kernel(const float* __restrict__ x,
                            const float* __restrict__ Wq,
                            const float* __restrict__ Wk,
                            const float* __restrict__ Wv,
                            const float* __restrict__ Wo,
                            unsigned short* __restrict__ x_bf,
                            unsigned short* __restrict__ w3,    // [3*512][512] B^T form
                            unsigned short* __restrict__ wo_t)  // [512][512]  B^T form
{
  int idx = blockIdx.x * 256 + threadIdx.x;
  const int NX = NB * NS * ND;  // 4194304
  const int NW = 512 * 512;     // 262144
  if (idx < NX) {
    x_bf[idx] = f2bf(x[idx]);
  } else if (idx < NX + 3 * NW) {
    int j = idx - NX;
    int p = j / NW;
    int r = j - p * NW;
    int n = r >> 9, d = r & 511;
    int h = n >> 6, o = n & 63;
    const float* W = (p == 0) ? Wq : (p == 1) ? Wk : Wv;
    w3[j] = f2bf(W[(h * 512 + d) * 64 + o]);  // w3[(p,n)][d] = W[h][d][o]
  } else if (idx < NX + 4 * NW) {
    int j = idx - NX - 3 * NW;
    int n = j >> 9, kk = j & 511;
    wo_t[j] = f2bf(Wo[kk * 512 + n]);  // wo_t[n][k] = Wo[k][n]
  }
}

// ---------------- GEMM: C[m][n] = sum_k A[m][k]*Bm[n][k], K=512 ------------
// MODE 0: fused QKV epilogue (bias, q*0.125, scatter q/k [bh,s,64], v [bh,64,s])
// MODE 1: output proj epilogue (bias bo, f32 row-major out)
template <int MODE>
__global__ void gemm_bt(const unsigned short* __restrict__ A,
                        const unsigned short* __restrict__ Bm,
                        const float* __restrict__ b0,
                        const float* __restrict__ b1,
                        const float* __restrict__ b2,
                        unsigned short* __restrict__ qo,
                        unsigned short* __restrict__ ko,
                        unsigned short* __restrict__ vo,
                        float* __restrict__ fo) {
  __shared__ unsigned short Al[128 * 32];
  __shared__ unsigned short Bl[128 * 32];
  const int t = threadIdx.x;
  const int m0 = blockIdx.x * 128;
  const int n0 = blockIdx.y * 128;
  const int lane = t & 63;
  const int w = t >> 6;
  const int wm = w >> 1, wn = w & 1;
  const int c = lane & 15, g = lane >> 4;

  f32x4 acc[4][4];
#pragma unroll
  for (int i = 0; i < 4; ++i)
#pragma unroll
    for (int j = 0; j < 4; ++j) acc[i][j] = (f32x4){0.f, 0.f, 0.f, 0.f};

  const int srow = t >> 1, sseg = (t & 1) * 16;
  const unsigned short* Ap = A + (size_t)(m0 + srow) * 512 + sseg;
  const unsigned short* Bp = Bm + (size_t)(n0 + srow) * 512 + sseg;
  unsigned short* Alp = &Al[srow * 32 + sseg];
  unsigned short* Blp = &Bl[srow * 32 + sseg];

  for (int k0 = 0; k0 < 512; k0 += 32) {
    bf16x8 ra0 = *(const bf16x8*)(Ap + k0);
    bf16x8 ra1 = *(const bf16x8*)(Ap + k0 + 8);
    bf16x8 rb0 = *(const bf16x8*)(Bp + k0);
    bf16x8 rb1 = *(const bf16x8*)(Bp + k0 + 8);
    __syncthreads();  // WAR: previous iteration's reads done before overwrite
    *(bf16x8*)(Alp) = ra0;
    *(bf16x8*)(Alp + 8) = ra1;
    *(bf16x8*)(Blp) = rb0;
    *(bf16x8*)(Blp + 8) = rb1;
    __syncthreads();  // RAW: stores visible
    bf16x8 af[4], bfr[4];
#pragma unroll
    for (int mf = 0; mf < 4; ++mf)
      af[mf] = *(const bf16x8*)&Al[(wm * 64 + mf * 16 + c) * 32 + g * 8];
#pragma unroll
    for (int nf = 0; nf < 4; ++nf)
      bfr[nf] = *(const bf16x8*)&Bl[(wn * 64 + nf * 16 + c) * 32 + g * 8];
#pragma unroll
    for (int mf = 0; mf < 4; ++mf)
#pragma unroll
      for (int nf = 0; nf < 4; ++nf)
        acc[mf][nf] = __builtin_amdgcn_mfma_f32_16x16x32_bf16(
            af[mf], bfr[nf], acc[mf][nf], 0, 0, 0);
  }

  if (MODE == 0) {
    const int proj = n0 >> 9;  // 0=q,1=k,2=v (tile never straddles)
    const float* bias = proj == 0 ? b0 : (proj == 1 ? b1 : b2);
    unsigned short* dst01 = proj == 0 ? qo : ko;
    const float scale = proj == 0 ? 0.125f : 1.0f;  // 1/sqrt(64), exact in bf16
#pragma unroll
    for (int nf = 0; nf < 4; ++nf) {
      const int col5 = (n0 + wn * 64 + nf * 16 + c) & 511;
      const int h = col5 >> 6, o = col5 & 63;
      const float bb = bias[col5];
#pragma unroll
      for (int mf = 0; mf < 4; ++mf) {
#pragma unroll
        for (int r = 0; r < 4; ++r) {
          const int m = m0 + wm * 64 + mf * 16 + g * 4 + r;
          const int b = m >> 12, s = m & 4095;
          const unsigned short hb = f2bf((acc[mf][nf][r] + bb) * scale);
          if (proj < 2)
            dst01[((size_t)((b * NH + h) * NS + s)) * 64 + o] = hb;
          else
            vo[((size_t)((b * NH + h) * 64 + o)) * NS + s] = hb;
        }
      }
    }
  } else {
#pragma unroll
    for (int nf = 0; nf < 4; ++nf) {
      const int col = n0 + wn * 64 + nf * 16 + c;
      const float bb = b0[col];
#pragma unroll
      for (int mf = 0; mf < 4; ++mf) {
#pragma unroll
        for (int r = 0; r < 4; ++r) {
          const int m = m0 + wm * 64 + mf * 16 + g * 4 + r;
          fo[(size_t)m * 512 + col] = acc[mf][nf][r] + bb;
        }
      }
    }
  }
}

// ---------------- flash attention: per block = (bh, 64 q-rows), 4 waves ----
__global__ void attn_kernel(const unsigned short* __restrict__ q,   // [bh][s][64]
                            const unsigned short* __restrict__ k,   // [bh][s][64]
                            const unsigned short* __restrict__ vt,  // [bh][64][s]
                            unsigned short* __restrict__ cc)        // [b][s][512]
{
  __shared__ unsigned short P[4][16][72];  // per-wave P tile, padded stride
  const int t = threadIdx.x;
  const int w = t >> 6, lane = t & 63;
  const int c = lane & 15, g = lane >> 4;
  const int bh = blockIdx.y;
  const int b = bh >> 3, h = bh & 7;
  const int qrow = blockIdx.x * 64 + w * 16;

  const unsigned short* qh = q + (size_t)bh * NS * 64;
  const unsigned short* kh = k + (size_t)bh * NS * 64;
  const unsigned short* vh = vt + (size_t)bh * 64 * NS;

  // Q fragments (q pre-scaled by 1/8): A-frag row = c, k = kf*32 + g*8 + j
  bf16x8 qf0 = *(const bf16x8*)&qh[(qrow + c) * 64 + g * 8];
  bf16x8 qf1 = *(const bf16x8*)&qh[(qrow + c) * 64 + 32 + g * 8];

  f32x4 oa[4];
#pragma unroll
  for (int nf = 0; nf < 4; ++nf) oa[nf] = (f32x4){0.f, 0.f, 0.f, 0.f};
  float m_[4], l_[4];
#pragma unroll
  for (int r = 0; r < 4; ++r) { m_[r] = -3.0e38f; l_[r] = 0.f; }

  for (int t0 = 0; t0 < NS; t0 += 64) {
    // S-tile = Q K^T : D[row=g*4+r][key=nf*16+c]
    f32x4 sa[4];
#pragma unroll
    for (int nf = 0; nf < 4; ++nf) sa[nf] = (f32x4){0.f, 0.f, 0.f, 0.f};
#pragma unroll
    for (int nf = 0; nf < 4; ++nf) {
      const unsigned short* kp = &kh[(size_t)(t0 + nf * 16 + c) * 64 + g * 8];
      bf16x8 kf0 = *(const bf16x8*)kp;
      bf16x8 kf1 = *(const bf16x8*)(kp + 32);
      sa[nf] = __builtin_amdgcn_mfma_f32_16x16x32_bf16(qf0, kf0, sa[nf], 0, 0, 0);
      sa[nf] = __builtin_amdgcn_mfma_f32_16x16x32_bf16(qf1, kf1, sa[nf], 0, 0, 0);
    }
    // online softmax: row r lives in 16 c-lanes of this g-group
    float mt[4];
#pragma unroll
    for (int r = 0; r < 4; ++r)
      mt[r] = fmaxf(fmaxf(sa[0][r], sa[1][r]), fmaxf(sa[2][r], sa[3][r]));
#pragma unroll
    for (int mask = 1; mask <= 8; mask <<= 1)
#pragma unroll
      for (int r = 0; r < 4; ++r) mt[r] = fmaxf(mt[r], __shfl_xor(mt[r], mask, 64));
    float resc[4], rs[4];
#pragma unroll
    for (int r = 0; r < 4; ++r) {
      float mn = fmaxf(m_[r], mt[r]);
      resc[r] = __expf(m_[r] - mn);
      m_[r] = mn;
      rs[r] = 0.f;
    }
#pragma unroll
    for (int nf = 0; nf < 4; ++nf)
#pragma unroll
      for (int r = 0; r < 4; ++r) {
        float p = __expf(sa[nf][r] - m_[r]);
        rs[r] += p;
        P[w][g * 4 + r][nf * 16 + c] = f2bf(p);
      }
#pragma unroll
    for (int mask = 1; mask <= 8; mask <<= 1)
#pragma unroll
      for (int r = 0; r < 4; ++r) rs[r] += __shfl_xor(rs[r], mask, 64);
#pragma unroll
    for (int r = 0; r < 4; ++r) l_[r] = l_[r] * resc[r] + rs[r];
#pragma unroll
    for (int nf = 0; nf < 4; ++nf) {
      f32x4 v = oa[nf];
      v[0] *= resc[0]; v[1] *= resc[1]; v[2] *= resc[2]; v[3] *= resc[3];
      oa[nf] = v;
    }
    // wait for this wave's P writes (per-wave tile; cross-lane RAW via LDS)
    asm volatile("s_waitcnt lgkmcnt(0)" ::: "memory");
    bf16x8 pf0 = *(const bf16x8*)&P[w][c][g * 8];
    bf16x8 pf1 = *(const bf16x8*)&P[w][c][32 + g * 8];
#pragma unroll
    for (int nf = 0; nf < 4; ++nf) {
      const unsigned short* vp = &vh[(size_t)(nf * 16 + c) * NS + t0 + g * 8];
      bf16x8 vf0 = *(const bf16x8*)vp;
      bf16x8 vf1 = *(const bf16x8*)(vp + 32);
      oa[nf] = __builtin_amdgcn_mfma_f32_16x16x32_bf16(pf0, vf0, oa[nf], 0, 0, 0);
      oa[nf] = __builtin_amdgcn_mfma_f32_16x16x32_bf16(pf1, vf1, oa[nf], 0, 0, 0);
    }
    // ensure P reads complete before next iteration's writes (WAR)
    asm volatile("s_waitcnt lgkmcnt(0)" ::: "memory");
  }
#pragma unroll
  for (int r = 0; r < 4; ++r) {
    const float inv = 1.0f / l_[r];
    const int srow = qrow + g * 4 + r;
#pragma unroll
    for (int nf = 0; nf < 4; ++nf) {
      cc[((size_t)(b * NS + srow)) * 512 + h * 64 + nf * 16 + c] =
          f2bf(oa[nf][r] * inv);
    }
  }
}

extern "C" void kernel_launch(void* const* d_in, const int* in_sizes, int n_in,
                              void* d_out, int out_size, void* d_ws, size_t ws_size,
                              hipStream_t stream) {
  const float* x  = (const float*)d_in[0];
  const float* Wq = (const float*)d_in[1];
  const float* bq = (const float*)d_in[2];
  const float* Wk = (const float*)d_in[3];
  const float* bk = (const float*)d_in[4];
  const float* Wv = (const float*)d_in[5];
  const float* bv = (const float*)d_in[6];
  const float* Wo = (const float*)d_in[7];
  const float* bo = (const float*)d_in[8];

  unsigned char* ws = (unsigned char*)d_ws;
  unsigned short* x_bf = (unsigned short*)(ws);              // 8 MB [8192][512]
  unsigned short* w3   = (unsigned short*)(ws + 8388608);    // 1.5 MB [1536][512]
  unsigned short* wo_t = (unsigned short*)(ws + 9961472);    // 0.5 MB [512][512]
  unsigned short* qb   = (unsigned short*)(ws + 10485760);   // 8 MB [16][4096][64]
  unsigned short* kb   = (unsigned short*)(ws + 18874368);   // 8 MB
  unsigned short* vb   = (unsigned short*)(ws + 27262976);   // 8 MB [16][64][4096]
  unsigned short* cc   = x_bf;  // reuse: x_bf dead after QKV GEMM

  pack_kernel<<<20480, 256, 0, stream>>>(x, Wq, Wk, Wv, Wo, x_bf, w3, wo_t);
  gemm_bt<0><<<dim3(64, 12), 256, 0, stream>>>(x_bf, w3, bq, bk, bv, qb, kb, vb,
                                               nullptr);
  attn_kernel<<<dim3(64, 16), 256, 0, stream>>>(qb, kb, vb, cc);
  gemm_bt<1><<<dim3(64, 4), 256, 0, stream>>>(cc, wo_t, bo, nullptr, nullptr,
                                              nullptr, nullptr, nullptr,
                                              (float*)d_out);
}

// Round 2
// 278.059 us; speedup vs baseline: 1.8415x; 1.8415x over previous
//
#include <hip/hip_runtime.h>
#include <hip/hip_bf16.h>

typedef __attribute__((ext_vector_type(8))) short bf16x8;
typedef __attribute__((ext_vector_type(4))) float f32x4;
typedef __attribute__((ext_vector_type(4))) unsigned short u16x4;

#define NB 2
#define NS 4096
#define ND 512
#define NH 8

__device__ __forceinline__ unsigned short f2bf(float f) {
  unsigned int u = __float_as_uint(f);
  u += 0x7fffu + ((u >> 16) & 1u);
  return (unsigned short)(u >> 16);
}

// ---------------- pack: fp32 -> bf16, pre-transpose weights ----------------
__global__ void pack_kernel(const float* __restrict__ x,
                            const float* __restrict__ Wq,
                            const float* __restrict__ Wk,
                            const float* __restrict__ Wv,
                            const float* __restrict__ Wo,
                            unsigned short* __restrict__ x_bf,
                            unsigned short* __restrict__ w3,    // [3*512][512] B^T form
                            unsigned short* __restrict__ wo_t)  // [512][512]  B^T form
{
  int idx = blockIdx.x * 256 + threadIdx.x;
  const int NX4 = NB * NS * ND / 4;  // 1048576 float4s
  const int NW = 512 * 512;          // 262144
  if (idx < NX4) {
    const float4 f = ((const float4*)x)[idx];
    u16x4 o;
    o[0] = f2bf(f.x); o[1] = f2bf(f.y); o[2] = f2bf(f.z); o[3] = f2bf(f.w);
    ((u16x4*)x_bf)[idx] = o;
  } else if (idx < NX4 + 3 * NW) {
    int j = idx - NX4;
    int p = j / NW;
    int r = j - p * NW;
    int n = r >> 9, d = r & 511;
    int h = n >> 6, o = n & 63;
    const float* W = (p == 0) ? Wq : (p == 1) ? Wk : Wv;
    w3[j] = f2bf(W[(h * 512 + d) * 64 + o]);  // w3[(p,n)][d] = W[h][d][o]
  } else if (idx < NX4 + 4 * NW) {
    int j = idx - NX4 - 3 * NW;
    int n = j >> 9, kk = j & 511;
    wo_t[j] = f2bf(Wo[kk * 512 + n]);  // wo_t[n][k] = Wo[k][n]
  }
}

// ---------------- GEMM: C[m][n] = sum_k A[m][k]*Bm[n][k], K=512 ------------
template <int MODE>
__global__ void gemm_bt(const unsigned short* __restrict__ A,
                        const unsigned short* __restrict__ Bm,
                        const float* __restrict__ b0,
                        const float* __restrict__ b1,
                        const float* __restrict__ b2,
                        unsigned short* __restrict__ qo,
                        unsigned short* __restrict__ ko,
                        unsigned short* __restrict__ vo,
                        float* __restrict__ fo) {
  __shared__ unsigned short Al[128 * 32];
  __shared__ unsigned short Bl[128 * 32];
  const int t = threadIdx.x;
  const int m0 = blockIdx.x * 128;
  const int n0 = blockIdx.y * 128;
  const int lane = t & 63;
  const int w = t >> 6;
  const int wm = w >> 1, wn = w & 1;
  const int c = lane & 15, g = lane >> 4;

  f32x4 acc[4][4];
#pragma unroll
  for (int i = 0; i < 4; ++i)
#pragma unroll
    for (int j = 0; j < 4; ++j) acc[i][j] = (f32x4){0.f, 0.f, 0.f, 0.f};

  const int srow = t >> 1, sseg = (t & 1) * 16;
  const unsigned short* Ap = A + (size_t)(m0 + srow) * 512 + sseg;
  const unsigned short* Bp = Bm + (size_t)(n0 + srow) * 512 + sseg;
  unsigned short* Alp = &Al[srow * 32 + sseg];
  unsigned short* Blp = &Bl[srow * 32 + sseg];

  for (int k0 = 0; k0 < 512; k0 += 32) {
    bf16x8 ra0 = *(const bf16x8*)(Ap + k0);
    bf16x8 ra1 = *(const bf16x8*)(Ap + k0 + 8);
    bf16x8 rb0 = *(const bf16x8*)(Bp + k0);
    bf16x8 rb1 = *(const bf16x8*)(Bp + k0 + 8);
    __syncthreads();
    *(bf16x8*)(Alp) = ra0;
    *(bf16x8*)(Alp + 8) = ra1;
    *(bf16x8*)(Blp) = rb0;
    *(bf16x8*)(Blp + 8) = rb1;
    __syncthreads();
    bf16x8 af[4], bfr[4];
#pragma unroll
    for (int mf = 0; mf < 4; ++mf)
      af[mf] = *(const bf16x8*)&Al[(wm * 64 + mf * 16 + c) * 32 + g * 8];
#pragma unroll
    for (int nf = 0; nf < 4; ++nf)
      bfr[nf] = *(const bf16x8*)&Bl[(wn * 64 + nf * 16 + c) * 32 + g * 8];
#pragma unroll
    for (int mf = 0; mf < 4; ++mf)
#pragma unroll
      for (int nf = 0; nf < 4; ++nf)
        acc[mf][nf] = __builtin_amdgcn_mfma_f32_16x16x32_bf16(
            af[mf], bfr[nf], acc[mf][nf], 0, 0, 0);
  }

  if (MODE == 0) {
    const int proj = n0 >> 9;  // 0=q,1=k,2=v
    const float* bias = proj == 0 ? b0 : (proj == 1 ? b1 : b2);
    unsigned short* dst01 = proj == 0 ? qo : ko;
    const float scale = proj == 0 ? 0.125f : 1.0f;
#pragma unroll
    for (int nf = 0; nf < 4; ++nf) {
      const int col5 = (n0 + wn * 64 + nf * 16 + c) & 511;
      const int h = col5 >> 6, o = col5 & 63;
      const float bb = bias[col5];
#pragma unroll
      for (int mf = 0; mf < 4; ++mf) {
#pragma unroll
        for (int r = 0; r < 4; ++r) {
          const int m = m0 + wm * 64 + mf * 16 + g * 4 + r;
          const int b = m >> 12, s = m & 4095;
          const unsigned short hb = f2bf((acc[mf][nf][r] + bb) * scale);
          if (proj < 2)
            dst01[((size_t)((b * NH + h) * NS + s)) * 64 + o] = hb;
          else
            vo[((size_t)((b * NH + h) * 64 + o)) * NS + s] = hb;
        }
      }
    }
  } else {
#pragma unroll
    for (int nf = 0; nf < 4; ++nf) {
      const int col = n0 + wn * 64 + nf * 16 + c;
      const float bb = b0[col];
#pragma unroll
      for (int mf = 0; mf < 4; ++mf) {
#pragma unroll
        for (int r = 0; r < 4; ++r) {
          const int m = m0 + wm * 64 + mf * 16 + g * 4 + r;
          fo[(size_t)m * 512 + col] = acc[mf][nf][r] + bb;
        }
      }
    }
  }
}

// ------- flash attention v2: 128 q-rows/block, 4 waves x 32 rows, LDS K/V --
// K tile LDS layout: row=key (0..63), 8 chunks of 16B, chunk ^= (row&7)
// V tile LDS layout: row=d   (0..63), same swizzle (vt is [bh][64][NS])
__global__ __launch_bounds__(256, 2) void attn_kernel(
    const unsigned short* __restrict__ q,   // [bh][s][64]
    const unsigned short* __restrict__ k,   // [bh][s][64]
    const unsigned short* __restrict__ vt,  // [bh][64][s]
    unsigned short* __restrict__ cc)        // [b][s][512]
{
  __shared__ unsigned short Kl[2][64 * 64];
  __shared__ unsigned short Vl[2][64 * 64];
  __shared__ unsigned short Pl[4][2][16][76];
  const int t = threadIdx.x;
  const int w = t >> 6, lane = t & 63;
  const int c = lane & 15, g = lane >> 4;
  const int bh = blockIdx.y;
  const int b = bh >> 3, h = bh & 7;
  const int q0 = blockIdx.x * 128;

  const unsigned short* qh = q + (size_t)bh * NS * 64;
  const unsigned short* kh = k + (size_t)bh * NS * 64;
  const unsigned short* vh = vt + (size_t)bh * 64 * NS;

  // Q fragments (pre-scaled by 1/8): wave rows q0 + w*32 + m*16 + c
  bf16x8 qf[2][2];
#pragma unroll
  for (int m = 0; m < 2; ++m)
#pragma unroll
    for (int kf = 0; kf < 2; ++kf)
      qf[m][kf] = *(const bf16x8*)&qh[(size_t)(q0 + w * 32 + m * 16 + c) * 64 +
                                      kf * 32 + g * 8];

  // staging geometry: 512 16B-chunks per 8KB tile, 256 threads x 2 passes
  const int r0 = t >> 3, r1 = r0 + 32;
  const int ch = t & 7;
  const int koff0 = r0 * 64 + ((ch ^ (r0 & 7)) << 3);
  const int koff1 = r1 * 64 + ((ch ^ (r1 & 7)) << 3);

  f32x4 oa[2][4];
  float m_[2][4], l_[2][4];
#pragma unroll
  for (int m = 0; m < 2; ++m) {
#pragma unroll
    for (int nf = 0; nf < 4; ++nf) oa[m][nf] = (f32x4){0.f, 0.f, 0.f, 0.f};
#pragma unroll
    for (int r = 0; r < 4; ++r) { m_[m][r] = -3.0e38f; l_[m][r] = 0.f; }
  }

  // prologue: stage tile 0 into buffer 0
  {
    bf16x8 a0 = *(const bf16x8*)&kh[(size_t)r0 * 64 + ch * 8];
    bf16x8 a1 = *(const bf16x8*)&kh[(size_t)r1 * 64 + ch * 8];
    bf16x8 v0 = *(const bf16x8*)&vh[(size_t)r0 * NS + ch * 8];
    bf16x8 v1 = *(const bf16x8*)&vh[(size_t)r1 * NS + ch * 8];
    *(bf16x8*)&Kl[0][koff0] = a0;
    *(bf16x8*)&Kl[0][koff1] = a1;
    *(bf16x8*)&Vl[0][koff0] = v0;
    *(bf16x8*)&Vl[0][koff1] = v1;
    __syncthreads();
  }

  const int NT = NS / 64;
  for (int it = 0; it < NT; ++it) {
    const int cur = it & 1;
    // prefetch next tile to registers (latency hidden under compute)
    bf16x8 pk0, pk1, pv0, pv1;
    if (it + 1 < NT) {
      const int tn = (it + 1) * 64;
      pk0 = *(const bf16x8*)&kh[(size_t)(tn + r0) * 64 + ch * 8];
      pk1 = *(const bf16x8*)&kh[(size_t)(tn + r1) * 64 + ch * 8];
      pv0 = *(const bf16x8*)&vh[(size_t)r0 * NS + tn + ch * 8];
      pv1 = *(const bf16x8*)&vh[(size_t)r1 * NS + tn + ch * 8];
    }

    // ---- QK^T: S[m] tiles, D[row=g*4+r][key=nf*16+c] ----
    f32x4 sa[2][4];
#pragma unroll
    for (int m = 0; m < 2; ++m)
#pragma unroll
      for (int nf = 0; nf < 4; ++nf) sa[m][nf] = (f32x4){0.f, 0.f, 0.f, 0.f};
#pragma unroll
    for (int nf = 0; nf < 4; ++nf) {
      const int row = nf * 16 + c;
      bf16x8 kf0 = *(const bf16x8*)&Kl[cur][row * 64 + ((g ^ (row & 7)) << 3)];
      bf16x8 kf1 =
          *(const bf16x8*)&Kl[cur][row * 64 + (((4 + g) ^ (row & 7)) << 3)];
#pragma unroll
      for (int m = 0; m < 2; ++m) {
        sa[m][nf] =
            __builtin_amdgcn_mfma_f32_16x16x32_bf16(qf[m][0], kf0, sa[m][nf], 0, 0, 0);
        sa[m][nf] =
            __builtin_amdgcn_mfma_f32_16x16x32_bf16(qf[m][1], kf1, sa[m][nf], 0, 0, 0);
      }
    }

    // ---- online softmax (per m-fragment; row r in 16 c-lanes of group g) --
#pragma unroll
    for (int m = 0; m < 2; ++m) {
      float mt[4];
#pragma unroll
      for (int r = 0; r < 4; ++r)
        mt[r] = fmaxf(fmaxf(sa[m][0][r], sa[m][1][r]),
                      fmaxf(sa[m][2][r], sa[m][3][r]));
#pragma unroll
      for (int mask = 1; mask <= 8; mask <<= 1)
#pragma unroll
        for (int r = 0; r < 4; ++r)
          mt[r] = fmaxf(mt[r], __shfl_xor(mt[r], mask, 64));
      float resc[4], rs[4];
#pragma unroll
      for (int r = 0; r < 4; ++r) {
        float mn = fmaxf(m_[m][r], mt[r]);
        resc[r] = __expf(m_[m][r] - mn);
        m_[m][r] = mn;
        rs[r] = 0.f;
      }
#pragma unroll
      for (int nf = 0; nf < 4; ++nf)
#pragma unroll
        for (int r = 0; r < 4; ++r) {
          float p = __expf(sa[m][nf][r] - m_[m][r]);
          rs[r] += p;
          Pl[w][m][g * 4 + r][nf * 16 + c] = f2bf(p);
        }
#pragma unroll
      for (int mask = 1; mask <= 8; mask <<= 1)
#pragma unroll
        for (int r = 0; r < 4; ++r) rs[r] += __shfl_xor(rs[r], mask, 64);
#pragma unroll
      for (int r = 0; r < 4; ++r) l_[m][r] = l_[m][r] * resc[r] + rs[r];
#pragma unroll
      for (int nf = 0; nf < 4; ++nf) {
        f32x4 v = oa[m][nf];
        v[0] *= resc[0]; v[1] *= resc[1]; v[2] *= resc[2]; v[3] *= resc[3];
        oa[m][nf] = v;
      }
    }

    // ---- PV: P from per-wave LDS, V frags from swizzled tile ----
    asm volatile("s_waitcnt lgkmcnt(0)" ::: "memory");
    bf16x8 pf[2][2];
#pragma unroll
    for (int m = 0; m < 2; ++m) {
      pf[m][0] = *(const bf16x8*)&Pl[w][m][c][g * 8];
      pf[m][1] = *(const bf16x8*)&Pl[w][m][c][32 + g * 8];
    }
#pragma unroll
    for (int nf = 0; nf < 4; ++nf) {
      const int row = nf * 16 + c;
      bf16x8 vf0 = *(const bf16x8*)&Vl[cur][row * 64 + ((g ^ (row & 7)) << 3)];
      bf16x8 vf1 =
          *(const bf16x8*)&Vl[cur][row * 64 + (((4 + g) ^ (row & 7)) << 3)];
#pragma unroll
      for (int m = 0; m < 2; ++m) {
        oa[m][nf] =
            __builtin_amdgcn_mfma_f32_16x16x32_bf16(pf[m][0], vf0, oa[m][nf], 0, 0, 0);
        oa[m][nf] =
            __builtin_amdgcn_mfma_f32_16x16x32_bf16(pf[m][1], vf1, oa[m][nf], 0, 0, 0);
      }
    }
    asm volatile("s_waitcnt lgkmcnt(0)" ::: "memory");  // WAR before next P write

    // ---- stage next tile into the other buffer ----
    if (it + 1 < NT) {
      __syncthreads();  // all waves done reading buf[cur^1] (last read it-1)
      *(bf16x8*)&Kl[cur ^ 1][koff0] = pk0;
      *(bf16x8*)&Kl[cur ^ 1][koff1] = pk1;
      *(bf16x8*)&Vl[cur ^ 1][koff0] = pv0;
      *(bf16x8*)&Vl[cur ^ 1][koff1] = pv1;
      __syncthreads();  // writes visible before next iteration reads
    }
  }

  // ---- epilogue: normalize and write [b][s][512] ----
#pragma unroll
  for (int m = 0; m < 2; ++m)
#pragma unroll
    for (int r = 0; r < 4; ++r) {
      const float inv = 1.0f / l_[m][r];
      const int srow = q0 + w * 32 + m * 16 + g * 4 + r;
#pragma unroll
      for (int nf = 0; nf < 4; ++nf) {
        cc[((size_t)(b * NS + srow)) * 512 + h * 64 + nf * 16 + c] =
            f2bf(oa[m][nf][r] * inv);
      }
    }
}

extern "C" void kernel_launch(void* const* d_in, const int* in_sizes, int n_in,
                              void* d_out, int out_size, void* d_ws, size_t ws_size,
                              hipStream_t stream) {
  const float* x  = (const float*)d_in[0];
  const float* Wq = (const float*)d_in[1];
  const float* bq = (const float*)d_in[2];
  const float* Wk = (const float*)d_in[3];
  const float* bk = (const float*)d_in[4];
  const float* Wv = (const float*)d_in[5];
  const float* bv = (const float*)d_in[6];
  const float* Wo = (const float*)d_in[7];
  const float* bo = (const float*)d_in[8];

  unsigned char* ws = (unsigned char*)d_ws;
  unsigned short* x_bf = (unsigned short*)(ws);              // 8 MB [8192][512]
  unsigned short* w3   = (unsigned short*)(ws + 8388608);    // 1.5 MB [1536][512]
  unsigned short* wo_t = (unsigned short*)(ws + 9961472);    // 0.5 MB [512][512]
  unsigned short* qb   = (unsigned short*)(ws + 10485760);   // 8 MB [16][4096][64]
  unsigned short* kb   = (unsigned short*)(ws + 18874368);   // 8 MB
  unsigned short* vb   = (unsigned short*)(ws + 27262976);   // 8 MB [16][64][4096]
  unsigned short* cc   = x_bf;  // reuse: x_bf dead after QKV GEMM

  pack_kernel<<<8192, 256, 0, stream>>>(x, Wq, Wk, Wv, Wo, x_bf, w3, wo_t);
  gemm_bt<0><<<dim3(64, 12), 256, 0, stream>>>(x_bf, w3, bq, bk, bv, qb, kb, vb,
                                               nullptr);
  attn_kernel<<<dim3(32, 16), 256, 0, stream>>>(qb, kb, vb, cc);
  gemm_bt<1><<<dim3(64, 4), 256, 0, stream>>>(cc, wo_t, bo, nullptr, nullptr,
                                              nullptr, nullptr, nullptr,
                                              (float*)d_out);
}

// Round 3
// 154.080 us; speedup vs baseline: 3.3233x; 1.8046x over previous
//
#include <hip/hip_runtime.h>
#include <hip/hip_bf16.h>

typedef __attribute__((ext_vector_type(8))) short bf16x8;
typedef __attribute__((ext_vector_type(4))) float f32x4;
typedef __attribute__((ext_vector_type(16))) float f32x16;
typedef __attribute__((ext_vector_type(4))) unsigned short u16x4;
typedef __attribute__((ext_vector_type(4))) unsigned int u32x4;

#define NB 2
#define NS 4096
#define ND 512
#define NH 8

__device__ __forceinline__ unsigned short f2bf(float f) {
  unsigned int u = __float_as_uint(f);
  u += 0x7fffu + ((u >> 16) & 1u);
  return (unsigned short)(u >> 16);
}

__device__ __forceinline__ float exp2_hw(float x) {
  float r;
  asm("v_exp_f32 %0, %1" : "=v"(r) : "v"(x));
  return r;
}

__device__ __forceinline__ unsigned cvtpk(float lo, float hi) {
  unsigned r;
  asm("v_cvt_pk_bf16_f32 %0, %1, %2" : "=v"(r) : "v"(lo), "v"(hi));
  return r;
}

// After: a = w-low (j0..3 source-half word), b = w-high (j4..7 word).
// Semantics (per guide m214 call shape): upper 32 lanes of a swap with
// lower 32 lanes of b.
__device__ __forceinline__ void swap32(unsigned& a, unsigned& b) {
  asm("v_permlane32_swap_b32 %0, %1" : "+v"(a), "+v"(b));
}

__device__ __forceinline__ bf16x8 mkfrag(unsigned w0, unsigned w1,
                                         unsigned w2, unsigned w3) {
  u32x4 u = {w0, w1, w2, w3};
  return __builtin_bit_cast(bf16x8, u);
}

// ---------------- pack: fp32 -> bf16, pre-transpose weights ----------------
__global__ void pack_kernel(const float* __restrict__ x,
                            const float* __restrict__ Wq,
                            const float* __restrict__ Wk,
                            const float* __restrict__ Wv,
                            const float* __restrict__ Wo,
                            unsigned short* __restrict__ x_bf,
                            unsigned short* __restrict__ w3,    // [3*512][512]
                            unsigned short* __restrict__ wo_t)  // [512][512]
{
  int idx = blockIdx.x * 256 + threadIdx.x;
  const int NX4 = NB * NS * ND / 4;  // 1048576 float4s
  const int NW = 512 * 512;          // 262144
  if (idx < NX4) {
    const float4 f = ((const float4*)x)[idx];
    u16x4 o;
    o[0] = f2bf(f.x); o[1] = f2bf(f.y); o[2] = f2bf(f.z); o[3] = f2bf(f.w);
    ((u16x4*)x_bf)[idx] = o;
  } else if (idx < NX4 + 3 * NW) {
    int j = idx - NX4;
    int p = j / NW;
    int r = j - p * NW;
    int n = r >> 9, d = r & 511;
    int h = n >> 6, o = n & 63;
    const float* W = (p == 0) ? Wq : (p == 1) ? Wk : Wv;
    w3[j] = f2bf(W[(h * 512 + d) * 64 + o]);
  } else if (idx < NX4 + 4 * NW) {
    int j = idx - NX4 - 3 * NW;
    int n = j >> 9, kk = j & 511;
    wo_t[j] = f2bf(Wo[kk * 512 + n]);
  }
}

// ---------------- GEMM: C[m][n] = sum_k A[m][k]*Bm[n][k], K=512 ------------
template <int MODE>
__global__ void gemm_bt(const unsigned short* __restrict__ A,
                        const unsigned short* __restrict__ Bm,
                        const float* __restrict__ b0,
                        const float* __restrict__ b1,
                        const float* __restrict__ b2,
                        unsigned short* __restrict__ qo,
                        unsigned short* __restrict__ ko,
                        unsigned short* __restrict__ vo,
                        float* __restrict__ fo) {
  __shared__ unsigned short Al[128 * 32];
  __shared__ unsigned short Bl[128 * 32];
  const int t = threadIdx.x;
  const int m0 = blockIdx.x * 128;
  const int n0 = blockIdx.y * 128;
  const int lane = t & 63;
  const int w = t >> 6;
  const int wm = w >> 1, wn = w & 1;
  const int c = lane & 15, g = lane >> 4;

  f32x4 acc[4][4];
#pragma unroll
  for (int i = 0; i < 4; ++i)
#pragma unroll
    for (int j = 0; j < 4; ++j) acc[i][j] = (f32x4){0.f, 0.f, 0.f, 0.f};

  const int srow = t >> 1, sseg = (t & 1) * 16;
  const unsigned short* Ap = A + (size_t)(m0 + srow) * 512 + sseg;
  const unsigned short* Bp = Bm + (size_t)(n0 + srow) * 512 + sseg;
  unsigned short* Alp = &Al[srow * 32 + sseg];
  unsigned short* Blp = &Bl[srow * 32 + sseg];

  for (int k0 = 0; k0 < 512; k0 += 32) {
    bf16x8 ra0 = *(const bf16x8*)(Ap + k0);
    bf16x8 ra1 = *(const bf16x8*)(Ap + k0 + 8);
    bf16x8 rb0 = *(const bf16x8*)(Bp + k0);
    bf16x8 rb1 = *(const bf16x8*)(Bp + k0 + 8);
    __syncthreads();
    *(bf16x8*)(Alp) = ra0;
    *(bf16x8*)(Alp + 8) = ra1;
    *(bf16x8*)(Blp) = rb0;
    *(bf16x8*)(Blp + 8) = rb1;
    __syncthreads();
    bf16x8 af[4], bfr[4];
#pragma unroll
    for (int mf = 0; mf < 4; ++mf)
      af[mf] = *(const bf16x8*)&Al[(wm * 64 + mf * 16 + c) * 32 + g * 8];
#pragma unroll
    for (int nf = 0; nf < 4; ++nf)
      bfr[nf] = *(const bf16x8*)&Bl[(wn * 64 + nf * 16 + c) * 32 + g * 8];
#pragma unroll
    for (int mf = 0; mf < 4; ++mf)
#pragma unroll
      for (int nf = 0; nf < 4; ++nf)
        acc[mf][nf] = __builtin_amdgcn_mfma_f32_16x16x32_bf16(
            af[mf], bfr[nf], acc[mf][nf], 0, 0, 0);
  }

  if (MODE == 0) {
    const int proj = n0 >> 9;  // 0=q,1=k,2=v
    const float* bias = proj == 0 ? b0 : (proj == 1 ? b1 : b2);
    unsigned short* dst01 = proj == 0 ? qo : ko;
    // q pre-scale folds 1/sqrt(64) AND log2(e) so attention can use exp2
    const float scale = proj == 0 ? 0.18033688011112042f : 1.0f;
#pragma unroll
    for (int nf = 0; nf < 4; ++nf) {
      const int col5 = (n0 + wn * 64 + nf * 16 + c) & 511;
      const int h = col5 >> 6, o = col5 & 63;
      const float bb = bias[col5];
#pragma unroll
      for (int mf = 0; mf < 4; ++mf) {
#pragma unroll
        for (int r = 0; r < 4; ++r) {
          const int m = m0 + wm * 64 + mf * 16 + g * 4 + r;
          const int b = m >> 12, s = m & 4095;
          const unsigned short hb = f2bf((acc[mf][nf][r] + bb) * scale);
          if (proj < 2)
            dst01[((size_t)((b * NH + h) * NS + s)) * 64 + o] = hb;
          else
            vo[((size_t)((b * NH + h) * 64 + o)) * NS + s] = hb;
        }
      }
    }
  } else {
#pragma unroll
    for (int nf = 0; nf < 4; ++nf) {
      const int col = n0 + wn * 64 + nf * 16 + c;
      const float bb = b0[col];
#pragma unroll
      for (int mf = 0; mf < 4; ++mf) {
#pragma unroll
        for (int r = 0; r < 4; ++r) {
          const int m = m0 + wm * 64 + mf * 16 + g * 4 + r;
          fo[(size_t)m * 512 + col] = acc[mf][nf][r] + bb;
        }
      }
    }
  }
}

// ------- flash attention v3: swapped-operand 32x32x16, lane-local softmax --
// Per block: 128 q-rows (4 waves x 32), KVBLK=64, K/V^T double-buffered LDS.
// QK^T: S^T = mfma(A=K, B=Q)  -> lane holds q-row (col=lane&31), 32 keys.
// PV:   O^T = mfma(A=V^T, B=P^T) -> O, m, l, rescale all lane-local.
__global__ __launch_bounds__(256, 2) void attn_kernel(
    const unsigned short* __restrict__ q,   // [bh][s][64] (pre-scaled, log2e)
    const unsigned short* __restrict__ k,   // [bh][s][64]
    const unsigned short* __restrict__ vt,  // [bh][64][s]
    unsigned short* __restrict__ cc)        // [b][s][512]
{
  __shared__ unsigned short Kl[2][64 * 64];
  __shared__ unsigned short Vl[2][64 * 64];
  __shared__ unsigned short Ol[4][32][68];
  const int t = threadIdx.x;
  const int w = t >> 6, lane = t & 63;
  const int col = lane & 31, hi = lane >> 5;
  const int bh = blockIdx.y;
  const int b = bh >> 3, h = bh & 7;
  const int q0 = blockIdx.x * 128 + w * 32;  // this wave's 32 q-rows

  const unsigned short* qh = q + (size_t)bh * NS * 64;
  const unsigned short* kh = k + (size_t)bh * NS * 64;
  const unsigned short* vh = vt + (size_t)bh * 64 * NS;

  // Q as B-operand: B[k=d][n=qrow]; lane: qrow=col, d = 16c + 8*hi + j
  bf16x8 qf[4];
#pragma unroll
  for (int c = 0; c < 4; ++c)
    qf[c] = *(const bf16x8*)&qh[(size_t)(q0 + col) * 64 + c * 16 + hi * 8];

  // staging geometry (identical to proven round-2 layout, 0 conflicts)
  const int r0 = t >> 3, r1 = r0 + 32;
  const int ch = t & 7;
  const int koff0 = r0 * 64 + ((ch ^ (r0 & 7)) << 3);
  const int koff1 = r1 * 64 + ((ch ^ (r1 & 7)) << 3);

  f32x16 ot0, ot1;
#pragma unroll
  for (int r = 0; r < 16; ++r) { ot0[r] = 0.f; ot1[r] = 0.f; }
  float m_ = -1.0e30f, l_ = 0.f;

  {  // prologue: stage tile 0 into buffer 0
    bf16x8 a0 = *(const bf16x8*)&kh[(size_t)r0 * 64 + ch * 8];
    bf16x8 a1 = *(const bf16x8*)&kh[(size_t)r1 * 64 + ch * 8];
    bf16x8 v0 = *(const bf16x8*)&vh[(size_t)r0 * NS + ch * 8];
    bf16x8 v1 = *(const bf16x8*)&vh[(size_t)r1 * NS + ch * 8];
    *(bf16x8*)&Kl[0][koff0] = a0;
    *(bf16x8*)&Kl[0][koff1] = a1;
    *(bf16x8*)&Vl[0][koff0] = v0;
    *(bf16x8*)&Vl[0][koff1] = v1;
    __syncthreads();
  }

  const int NT = NS / 64;
  for (int it = 0; it < NT; ++it) {
    const int cur = it & 1;
    bf16x8 pk0, pk1, pv0, pv1;
    if (it + 1 < NT) {
      const int tn = (it + 1) * 64;
      pk0 = *(const bf16x8*)&kh[(size_t)(tn + r0) * 64 + ch * 8];
      pk1 = *(const bf16x8*)&kh[(size_t)(tn + r1) * 64 + ch * 8];
      pv0 = *(const bf16x8*)&vh[(size_t)r0 * NS + tn + ch * 8];
      pv1 = *(const bf16x8*)&vh[(size_t)r1 * NS + tn + ch * 8];
    }

    // ---- S^T = K · Q^T : p0 = keys[0..31], p1 = keys[32..63] ----
    f32x16 p0, p1;
#pragma unroll
    for (int r = 0; r < 16; ++r) { p0[r] = 0.f; p1[r] = 0.f; }
#pragma unroll
    for (int c = 0; c < 4; ++c) {
      const int cidx = (((2 * c + hi) ^ (col & 7)) << 3);
      bf16x8 kf0 = *(const bf16x8*)&Kl[cur][col * 64 + cidx];
      bf16x8 kf1 = *(const bf16x8*)&Kl[cur][(col + 32) * 64 + cidx];
      p0 = __builtin_amdgcn_mfma_f32_32x32x16_bf16(kf0, qf[c], p0, 0, 0, 0);
      p1 = __builtin_amdgcn_mfma_f32_32x32x16_bf16(kf1, qf[c], p1, 0, 0, 0);
    }

    // ---- lane-local online softmax (log2 domain) ----
    float mx[8];
#pragma unroll
    for (int r = 0; r < 8; ++r)
      mx[r] = fmaxf(fmaxf(p0[r], p0[r + 8]), fmaxf(p1[r], p1[r + 8]));
#pragma unroll
    for (int s = 4; s >= 1; s >>= 1)
#pragma unroll
      for (int r = 0; r < 8; ++r)
        if (r < s) mx[r] = fmaxf(mx[r], mx[r + s]);
    float pm = mx[0];
    pm = fmaxf(pm, __shfl_xor(pm, 32, 64));
    if (__any(pm > m_ + 8.f)) {  // defer-max: rescale only on real growth
      const float resc = exp2_hw(m_ - pm);
      m_ = pm;
      l_ *= resc;
#pragma unroll
      for (int r = 0; r < 16; ++r) { ot0[r] *= resc; ot1[r] *= resc; }
    }
    float e0[16], e1[16];
#pragma unroll
    for (int r = 0; r < 16; ++r) {
      e0[r] = exp2_hw(p0[r] - m_);
      e1[r] = exp2_hw(p1[r] - m_);
    }
    float sm[8];
#pragma unroll
    for (int r = 0; r < 8; ++r)
      sm[r] = (e0[r] + e0[r + 8]) + (e1[r] + e1[r + 8]);
#pragma unroll
    for (int s = 4; s >= 1; s >>= 1)
#pragma unroll
      for (int r = 0; r < 8; ++r)
        if (r < s) sm[r] += sm[r + s];
    float rs = sm[0];
    rs += __shfl_xor(rs, 32, 64);
    l_ += rs;

    // ---- P -> bf16 B-fragments in-register (cvt_pk + permlane32_swap) ----
    unsigned g0[8], g1[8];
#pragma unroll
    for (int gg = 0; gg < 8; ++gg) {
      g0[gg] = cvtpk(e0[2 * gg], e0[2 * gg + 1]);
      g1[gg] = cvtpk(e1[2 * gg], e1[2 * gg + 1]);
    }
    bf16x8 pb[4];
    {
      unsigned a, c2, b2, d2;
      a = g0[0]; b2 = g0[2]; swap32(a, b2);
      c2 = g0[1]; d2 = g0[3]; swap32(c2, d2);
      pb[0] = mkfrag(a, c2, b2, d2);
      a = g0[4]; b2 = g0[6]; swap32(a, b2);
      c2 = g0[5]; d2 = g0[7]; swap32(c2, d2);
      pb[1] = mkfrag(a, c2, b2, d2);
      a = g1[0]; b2 = g1[2]; swap32(a, b2);
      c2 = g1[1]; d2 = g1[3]; swap32(c2, d2);
      pb[2] = mkfrag(a, c2, b2, d2);
      a = g1[4]; b2 = g1[6]; swap32(a, b2);
      c2 = g1[5]; d2 = g1[7]; swap32(c2, d2);
      pb[3] = mkfrag(a, c2, b2, d2);
    }

    // ---- O^T += V^T · P^T ----
#pragma unroll
    for (int ks = 0; ks < 4; ++ks) {
      const int cidx = (((2 * ks + hi) ^ (col & 7)) << 3);
      bf16x8 vf0 = *(const bf16x8*)&Vl[cur][col * 64 + cidx];
      bf16x8 vf1 = *(const bf16x8*)&Vl[cur][(col + 32) * 64 + cidx];
      ot0 = __builtin_amdgcn_mfma_f32_32x32x16_bf16(vf0, pb[ks], ot0, 0, 0, 0);
      ot1 = __builtin_amdgcn_mfma_f32_32x32x16_bf16(vf1, pb[ks], ot1, 0, 0, 0);
    }

    // ---- stage next tile into the other buffer ----
    if (it + 1 < NT) {
      __syncthreads();
      *(bf16x8*)&Kl[cur ^ 1][koff0] = pk0;
      *(bf16x8*)&Kl[cur ^ 1][koff1] = pk1;
      *(bf16x8*)&Vl[cur ^ 1][koff0] = pv0;
      *(bf16x8*)&Vl[cur ^ 1][koff1] = pv1;
      __syncthreads();
    }
  }

  // ---- epilogue: normalize, transpose via LDS, coalesced store ----
  const float inv = 1.0f / l_;
#pragma unroll
  for (int r = 0; r < 16; ++r) {
    const int dvb = (r & 3) + 8 * (r >> 2) + 4 * hi;
    Ol[w][col][dvb] = f2bf(ot0[r] * inv);
    Ol[w][col][dvb + 32] = f2bf(ot1[r] * inv);
  }
  asm volatile("s_waitcnt lgkmcnt(0)" ::: "memory");
  const int row = lane >> 1;
#pragma unroll
  for (int p = 0; p < 4; ++p) {
    const int chunk = (lane & 1) + 2 * p;
    bf16x8 vv = *(const bf16x8*)&Ol[w][row][chunk * 8];
    *(bf16x8*)&cc[((size_t)(b * NS + q0 + row)) * 512 + h * 64 + chunk * 8] = vv;
  }
}

extern "C" void kernel_launch(void* const* d_in, const int* in_sizes, int n_in,
                              void* d_out, int out_size, void* d_ws, size_t ws_size,
                              hipStream_t stream) {
  const float* x  = (const float*)d_in[0];
  const float* Wq = (const float*)d_in[1];
  const float* bq = (const float*)d_in[2];
  const float* Wk = (const float*)d_in[3];
  const float* bk = (const float*)d_in[4];
  const float* Wv = (const float*)d_in[5];
  const float* bv = (const float*)d_in[6];
  const float* Wo = (const float*)d_in[7];
  const float* bo = (const float*)d_in[8];

  unsigned char* ws = (unsigned char*)d_ws;
  unsigned short* x_bf = (unsigned short*)(ws);              // 8 MB [8192][512]
  unsigned short* w3   = (unsigned short*)(ws + 8388608);    // 1.5 MB [1536][512]
  unsigned short* wo_t = (unsigned short*)(ws + 9961472);    // 0.5 MB [512][512]
  unsigned short* qb   = (unsigned short*)(ws + 10485760);   // 8 MB [16][4096][64]
  unsigned short* kb   = (unsigned short*)(ws + 18874368);   // 8 MB
  unsigned short* vb   = (unsigned short*)(ws + 27262976);   // 8 MB [16][64][4096]
  unsigned short* cc   = x_bf;  // reuse: x_bf dead after QKV GEMM

  pack_kernel<<<8192, 256, 0, stream>>>(x, Wq, Wk, Wv, Wo, x_bf, w3, wo_t);
  gemm_bt<0><<<dim3(64, 12), 256, 0, stream>>>(x_bf, w3, bq, bk, bv, qb, kb, vb,
                                               nullptr);
  attn_kernel<<<dim3(32, 16), 256, 0, stream>>>(qb, kb, vb, cc);
  gemm_bt<1><<<dim3(64, 4), 256, 0, stream>>>(cc, wo_t, bo, nullptr, nullptr,
                                              nullptr, nullptr, nullptr,
                                              (float*)d_out);
}